// Round 1
// baseline (2186.675 us; speedup 1.0000x reference)
//
#include <hip/hip_runtime.h>
#include <math.h>

#define HIDDEN 2048
#define NHEADS 32
#define GSIZE 4
#define HDIM 64
#define GNUM 8
#define KVDIM 512
#define BB 2
#define SS 2048

// C[M,N] = A[M,K] @ W[K,N] + bias[N]   (all f32, row-major)
__global__ __launch_bounds__(256)
void gemm_bias(const float* __restrict__ A, const float* __restrict__ W,
               const float* __restrict__ bias, float* __restrict__ C,
               int M, int N, int K) {
    __shared__ float As[32][65];   // transposed: As[k][m], +1 pad
    __shared__ float Ws[32][65];   // Ws[k][n], +1 pad
    const int tid = threadIdx.x;
    const int tx = tid & 15;       // N microtile
    const int ty = tid >> 4;       // M microtile
    const int bm = blockIdx.x, bn = blockIdx.y;
    const float* Ab = A + (size_t)bm * 64 * K;
    const float* Wb = W + (size_t)bn * 64;
    float acc[4][4] = {};

    for (int k0 = 0; k0 < K; k0 += 32) {
        #pragma unroll
        for (int i = 0; i < 2; ++i) {
            int idx = tid + i * 256;           // 0..511
            int r  = idx >> 3, c4 = idx & 7;   // A tile 64x32: 8 float4/row
            float4 av = *reinterpret_cast<const float4*>(Ab + (size_t)r * K + k0 + c4 * 4);
            As[c4 * 4 + 0][r] = av.x;
            As[c4 * 4 + 1][r] = av.y;
            As[c4 * 4 + 2][r] = av.z;
            As[c4 * 4 + 3][r] = av.w;
            int rw = idx >> 4, cw4 = idx & 15; // W tile 32x64: 16 float4/row
            float4 wv = *reinterpret_cast<const float4*>(Wb + (size_t)(k0 + rw) * N + cw4 * 4);
            Ws[rw][cw4 * 4 + 0] = wv.x;
            Ws[rw][cw4 * 4 + 1] = wv.y;
            Ws[rw][cw4 * 4 + 2] = wv.z;
            Ws[rw][cw4 * 4 + 3] = wv.w;
        }
        __syncthreads();
        #pragma unroll 8
        for (int kk = 0; kk < 32; ++kk) {
            float a[4], w[4];
            #pragma unroll
            for (int i = 0; i < 4; ++i) a[i] = As[kk][ty * 4 + i];
            #pragma unroll
            for (int j = 0; j < 4; ++j) w[j] = Ws[kk][tx * 4 + j];
            #pragma unroll
            for (int i = 0; i < 4; ++i)
                #pragma unroll
                for (int j = 0; j < 4; ++j)
                    acc[i][j] = fmaf(a[i], w[j], acc[i][j]);
        }
        __syncthreads();
    }

    #pragma unroll
    for (int i = 0; i < 4; ++i) {
        float4 r4;
        r4.x = acc[i][0] + bias[bn * 64 + tx * 4 + 0];
        r4.y = acc[i][1] + bias[bn * 64 + tx * 4 + 1];
        r4.z = acc[i][2] + bias[bn * 64 + tx * 4 + 2];
        r4.w = acc[i][3] + bias[bn * 64 + tx * 4 + 3];
        *reinterpret_cast<float4*>(&C[(size_t)(bm * 64 + ty * 4 + i) * N + bn * 64 + tx * 4]) = r4;
    }
}

// Fused attention (no softmax): out = floor(Q Kᵀ / 8) @ V, with mask
// grid: (S/64, B*NHEADS); one block = one (b, h, 64-row q-tile)
__global__ __launch_bounds__(256)
void attn(const float* __restrict__ q, const float* __restrict__ k,
          const float* __restrict__ v, const int* __restrict__ mask,
          float* __restrict__ out) {
    __shared__ float Qs[64][65];
    __shared__ float Ks[64][68];
    __shared__ float Vs[64][68];
    __shared__ float Ss[64][65];
    const int tid = threadIdx.x;
    const int tx = tid & 15;     // col microtile (scores: k-cols; SV: dims)
    const int ty = tid >> 4;     // row microtile (q rows)
    const int qt = blockIdx.x;
    const int bh = blockIdx.y;
    const int b = bh >> 5, h = bh & 31, g = h >> 2;

    // load Q tile (64 rows x 64 dims), coalesced scalar
    const float* qb = q + ((size_t)(b * SS + qt * 64)) * HIDDEN + h * HDIM;
    #pragma unroll
    for (int i = 0; i < 16; ++i) {
        int idx = tid + i * 256;
        int rr = idx >> 6, cc = idx & 63;
        Qs[rr][cc] = qb[(size_t)rr * HIDDEN + cc];
    }

    const float* kb = k + (size_t)b * SS * KVDIM + g * HDIM;
    const float* vb = v + (size_t)b * SS * KVDIM + g * HDIM;
    const int* mb = mask + b * SS;
    float o[4][4] = {};

    for (int kt = 0; kt < SS / 64; ++kt) {
        __syncthreads();   // protect Ks/Vs from previous iteration's readers
        #pragma unroll
        for (int i = 0; i < 4; ++i) {
            int idx = tid + i * 256;            // 0..1023 float4s
            int rr = idx >> 4, c4 = idx & 15;
            float4 kv4 = *reinterpret_cast<const float4*>(kb + (size_t)(kt * 64 + rr) * KVDIM + c4 * 4);
            *reinterpret_cast<float4*>(&Ks[rr][c4 * 4]) = kv4;
            float4 vv4 = *reinterpret_cast<const float4*>(vb + (size_t)(kt * 64 + rr) * KVDIM + c4 * 4);
            *reinterpret_cast<float4*>(&Vs[rr][c4 * 4]) = vv4;
        }
        __syncthreads();

        // scores: 4x4 microtile rows ty*4.., cols tx*4..
        float sacc[4][4] = {};
        #pragma unroll 8
        for (int d = 0; d < 64; ++d) {
            float a[4], bb_[4];
            #pragma unroll
            for (int i = 0; i < 4; ++i) a[i] = Qs[ty * 4 + i][d];
            #pragma unroll
            for (int j = 0; j < 4; ++j) bb_[j] = Ks[tx * 4 + j][d];
            #pragma unroll
            for (int i = 0; i < 4; ++i)
                #pragma unroll
                for (int j = 0; j < 4; ++j)
                    sacc[i][j] = fmaf(a[i], bb_[j], sacc[i][j]);
        }
        int m4[4];
        #pragma unroll
        for (int j = 0; j < 4; ++j) m4[j] = mb[kt * 64 + tx * 4 + j];
        #pragma unroll
        for (int i = 0; i < 4; ++i)
            #pragma unroll
            for (int j = 0; j < 4; ++j) {
                float s = floorf(sacc[i][j] * 0.125f);
                if (m4[j] == 0) s = -INFINITY;
                Ss[ty * 4 + i][tx * 4 + j] = s;
            }
        __syncthreads();

        // SV: o[i][j], rows ty*4+i, dims tx*4+j
        #pragma unroll 8
        for (int jj = 0; jj < 64; ++jj) {
            float a[4], bb_[4];
            #pragma unroll
            for (int i = 0; i < 4; ++i) a[i] = Ss[ty * 4 + i][jj];
            #pragma unroll
            for (int j = 0; j < 4; ++j) bb_[j] = Vs[jj][tx * 4 + j];
            #pragma unroll
            for (int i = 0; i < 4; ++i)
                #pragma unroll
                for (int j = 0; j < 4; ++j)
                    o[i][j] = fmaf(a[i], bb_[j], o[i][j]);
        }
    }

    // write out: row (b, qt*64+ty*4+i), col h*64 + tx*4 + j  (float4 per row)
    #pragma unroll
    for (int i = 0; i < 4; ++i) {
        float4 r4;
        r4.x = o[i][0]; r4.y = o[i][1]; r4.z = o[i][2]; r4.w = o[i][3];
        *reinterpret_cast<float4*>(
            &out[((size_t)(b * SS + qt * 64 + ty * 4 + i)) * HIDDEN + h * HDIM + tx * 4]) = r4;
    }
}

extern "C" void kernel_launch(void* const* d_in, const int* in_sizes, int n_in,
                              void* d_out, int out_size, void* d_ws, size_t ws_size,
                              hipStream_t stream) {
    (void)in_sizes; (void)n_in; (void)out_size; (void)ws_size;
    const float* x    = (const float*)d_in[0];
    const int*   mask = (const int*)d_in[1];
    const float* Wq   = (const float*)d_in[2];
    const float* bq   = (const float*)d_in[3];
    const float* Wk   = (const float*)d_in[4];
    const float* bk   = (const float*)d_in[5];
    const float* Wv   = (const float*)d_in[6];
    const float* bv   = (const float*)d_in[7];
    float* out = (float*)d_out;

    float* qbuf = (float*)d_ws;                         // 4096*2048 f32 = 32 MB
    float* kbuf = qbuf + (size_t)BB * SS * HIDDEN;      // 4096*512  f32 =  8 MB
    float* vbuf = kbuf + (size_t)BB * SS * KVDIM;       // 4096*512  f32 =  8 MB

    const int M = BB * SS;
    dim3 blk(256);
    gemm_bias<<<dim3(M / 64, HIDDEN / 64), blk, 0, stream>>>(x, Wq, bq, qbuf, M, HIDDEN, HIDDEN);
    gemm_bias<<<dim3(M / 64, KVDIM / 64), blk, 0, stream>>>(x, Wk, bk, kbuf, M, KVDIM, HIDDEN);
    gemm_bias<<<dim3(M / 64, KVDIM / 64), blk, 0, stream>>>(x, Wv, bv, vbuf, M, KVDIM, HIDDEN);
    attn<<<dim3(SS / 64, BB * NHEADS), blk, 0, stream>>>(qbuf, kbuf, vbuf, mask, out);
}

// Round 2
// 945.796 us; speedup vs baseline: 2.3120x; 2.3120x over previous
//
#include <hip/hip_runtime.h>
#include <math.h>

#define HIDDEN 2048
#define NHEADS 32
#define HDIM 64
#define GNUM 8
#define KVDIM 512
#define BB 2
#define SS 2048

typedef _Float16 half8 __attribute__((ext_vector_type(8)));
typedef _Float16 half4 __attribute__((ext_vector_type(4)));
typedef _Float16 half2 __attribute__((ext_vector_type(2)));
typedef float floatx4 __attribute__((ext_vector_type(4)));

#define MFMA16(a, b, c) __builtin_amdgcn_mfma_f32_16x16x32_f16((a), (b), (c), 0, 0, 0)

// split x = hi + lo * 2^-11, lo scaled into fp16 normal range
__device__ __forceinline__ void split_f32(float x, _Float16& hi, _Float16& lo) {
    hi = (_Float16)x;
    lo = (_Float16)((x - (float)hi) * 2048.0f);
}

// ---------------------------------------------------------------------------
// C[M,N] = A[M,K] @ W[K,N] + bias[N], split-fp16 3-term MFMA, f32 in/out.
// 128x128 block tile, BK=32, 4 waves (2x2), wave tile 64x64.
// ---------------------------------------------------------------------------
__global__ __launch_bounds__(256, 2)
void gemm_split(const float* __restrict__ A, const float* __restrict__ W,
                const float* __restrict__ bias, float* __restrict__ C,
                int M, int N, int K) {
    __shared__ __align__(16) _Float16 As_h[128][32];
    __shared__ __align__(16) _Float16 As_l[128][32];
    __shared__ __align__(16) _Float16 Bs_h[128][32];   // transposed: [n][k]
    __shared__ __align__(16) _Float16 Bs_l[128][32];

    const int tid  = threadIdx.x;
    const int lane = tid & 63;
    const int w    = tid >> 6;
    const int wm   = w >> 1, wn = w & 1;
    const int bm   = blockIdx.x, bn = blockIdx.y;
    const int ml   = lane & 15;
    const int kg8  = (lane >> 4) * 8;

    floatx4 acc0[4][4] = {};
    floatx4 accL[4][4] = {};

    for (int k0 = 0; k0 < K; k0 += 32) {
        // --- stage A tile 128x32 (row-major, contiguous in k) ---
        #pragma unroll
        for (int i = 0; i < 4; ++i) {
            int idx = tid + i * 256;          // 0..1023
            int m = idx >> 3, k4 = idx & 7;
            floatx4 av = *reinterpret_cast<const floatx4*>(
                &A[(size_t)(bm * 128 + m) * K + k0 + k4 * 4]);
            half4 h4, l4;
            #pragma unroll
            for (int e = 0; e < 4; ++e) { _Float16 hi, lo; split_f32(av[e], hi, lo); h4[e] = hi; l4[e] = lo; }
            *reinterpret_cast<half4*>(&As_h[m][k4 * 4]) = h4;
            *reinterpret_cast<half4*>(&As_l[m][k4 * 4]) = l4;
        }
        // --- stage B tile 32x128 transposed to [n][k], 2 k-rows per thread ---
        #pragma unroll
        for (int i = 0; i < 2; ++i) {
            int idx = tid + i * 256;          // 0..511
            int kk = (idx >> 5) * 2, n4 = idx & 31;
            floatx4 w0 = *reinterpret_cast<const floatx4*>(
                &W[(size_t)(k0 + kk) * N + bn * 128 + n4 * 4]);
            floatx4 w1 = *reinterpret_cast<const floatx4*>(
                &W[(size_t)(k0 + kk + 1) * N + bn * 128 + n4 * 4]);
            #pragma unroll
            for (int e = 0; e < 4; ++e) {
                _Float16 h0, l0, h1, l1;
                split_f32(w0[e], h0, l0);
                split_f32(w1[e], h1, l1);
                int n = n4 * 4 + e;
                *reinterpret_cast<half2*>(&Bs_h[n][kk]) = half2{h0, h1};
                *reinterpret_cast<half2*>(&Bs_l[n][kk]) = half2{l0, l1};
            }
        }
        __syncthreads();

        half8 ah[4], al[4], bh[4], bl[4];
        #pragma unroll
        for (int r = 0; r < 4; ++r) {
            ah[r] = *reinterpret_cast<const half8*>(&As_h[wm * 64 + r * 16 + ml][kg8]);
            al[r] = *reinterpret_cast<const half8*>(&As_l[wm * 64 + r * 16 + ml][kg8]);
        }
        #pragma unroll
        for (int c = 0; c < 4; ++c) {
            bh[c] = *reinterpret_cast<const half8*>(&Bs_h[wn * 64 + c * 16 + ml][kg8]);
            bl[c] = *reinterpret_cast<const half8*>(&Bs_l[wn * 64 + c * 16 + ml][kg8]);
        }
        #pragma unroll
        for (int r = 0; r < 4; ++r)
            #pragma unroll
            for (int c = 0; c < 4; ++c) {
                acc0[r][c] = MFMA16(ah[r], bh[c], acc0[r][c]);
                accL[r][c] = MFMA16(ah[r], bl[c], accL[r][c]);
                accL[r][c] = MFMA16(al[r], bh[c], accL[r][c]);
            }
        __syncthreads();
    }

    // epilogue: C = acc0 + accL/2048 + bias   (C layout: col=lane&15, row=(lane>>4)*4+reg)
    #pragma unroll
    for (int c = 0; c < 4; ++c) {
        int col = bn * 128 + wn * 64 + c * 16 + ml;
        float bval = bias[col];
        #pragma unroll
        for (int r = 0; r < 4; ++r) {
            int row0 = bm * 128 + wm * 64 + r * 16 + (lane >> 4) * 4;
            #pragma unroll
            for (int reg = 0; reg < 4; ++reg)
                C[(size_t)(row0 + reg) * N + col] =
                    acc0[r][c][reg] + accL[r][c][reg] * (1.0f / 2048.0f) + bval;
        }
    }
}

// ---------------------------------------------------------------------------
// Fused attention: out = floor(QK^T/8, masked) @ V per (b,h), MFMA fp16.
// Block = (b, h, 64 q-rows); 4 waves, each owns 16 q-rows. KT=64 chunk.
// Q split-fp16 in registers; K staged hi/lo; V staged transposed fp16.
// ---------------------------------------------------------------------------
__global__ __launch_bounds__(256, 2)
void attn_mfma(const float* __restrict__ q, const float* __restrict__ k,
               const float* __restrict__ v, const int* __restrict__ mask,
               float* __restrict__ out) {
    __shared__ __align__(16) _Float16 Ks_h[64][72];
    __shared__ __align__(16) _Float16 Ks_l[64][72];
    __shared__ __align__(16) _Float16 Vs[64][72];     // transposed: [dim][k]
    __shared__ __align__(16) _Float16 Ss[4][16][72];  // per-wave scores

    const int tid  = threadIdx.x;
    const int lane = tid & 63;
    const int w    = tid >> 6;
    const int ml   = lane & 15;
    const int kg8  = (lane >> 4) * 8;
    const int qt   = blockIdx.x;
    const int bh   = blockIdx.y;
    const int b    = bh >> 5, h = bh & 31, g = h >> 2;

    // hoist Q fragments (16 rows per wave) into registers, split hi/lo
    const float* qrow = q + (size_t)(b * SS + qt * 64 + w * 16 + ml) * HIDDEN + h * HDIM;
    half8 qh_[2], ql_[2];
    #pragma unroll
    for (int gch = 0; gch < 2; ++gch) {
        floatx4 f0 = *reinterpret_cast<const floatx4*>(&qrow[gch * 32 + kg8]);
        floatx4 f1 = *reinterpret_cast<const floatx4*>(&qrow[gch * 32 + kg8 + 4]);
        #pragma unroll
        for (int e = 0; e < 4; ++e) {
            _Float16 hi, lo;
            split_f32(f0[e], hi, lo); qh_[gch][e] = hi;     ql_[gch][e] = lo;
            split_f32(f1[e], hi, lo); qh_[gch][e + 4] = hi; ql_[gch][e + 4] = lo;
        }
    }

    const float* kb = k + (size_t)b * SS * KVDIM + g * HDIM;
    const float* vb = v + (size_t)b * SS * KVDIM + g * HDIM;
    const int*   mb = mask + b * SS;

    floatx4 oacc[4] = {};

    for (int kt = 0; kt < SS / 64; ++kt) {
        __syncthreads();   // all waves done reading previous Ks/Vs
        // --- stage K (hi/lo) and V (transposed) ---
        #pragma unroll
        for (int i = 0; i < 4; ++i) {       // K: 64x64 f32
            int idx = tid + i * 256;        // 0..1023
            int kk = idx >> 4, d4 = idx & 15;
            floatx4 kv = *reinterpret_cast<const floatx4*>(
                &kb[(size_t)(kt * 64 + kk) * KVDIM + d4 * 4]);
            half4 h4, l4;
            #pragma unroll
            for (int e = 0; e < 4; ++e) { _Float16 hi, lo; split_f32(kv[e], hi, lo); h4[e] = hi; l4[e] = lo; }
            *reinterpret_cast<half4*>(&Ks_h[kk][d4 * 4]) = h4;
            *reinterpret_cast<half4*>(&Ks_l[kk][d4 * 4]) = l4;
        }
        #pragma unroll
        for (int i = 0; i < 2; ++i) {       // V: 64x64 f32, store [dim][k], 2 k per thread
            int idx = tid + i * 256;        // 0..511
            int kk = (idx >> 4) * 2, d4 = idx & 15;
            floatx4 v0 = *reinterpret_cast<const floatx4*>(
                &vb[(size_t)(kt * 64 + kk) * KVDIM + d4 * 4]);
            floatx4 v1 = *reinterpret_cast<const floatx4*>(
                &vb[(size_t)(kt * 64 + kk + 1) * KVDIM + d4 * 4]);
            #pragma unroll
            for (int e = 0; e < 4; ++e)
                *reinterpret_cast<half2*>(&Vs[d4 * 4 + e][kk]) =
                    half2{(_Float16)v0[e], (_Float16)v1[e]};
        }
        __syncthreads();

        // --- QK^T: 4 col-frags of 16 k-cols each ---
        #pragma unroll
        for (int fc = 0; fc < 4; ++fc) {
            floatx4 s0 = {}, sL = {};
            #pragma unroll
            for (int gch = 0; gch < 2; ++gch) {
                half8 kh8 = *reinterpret_cast<const half8*>(&Ks_h[fc * 16 + ml][gch * 32 + kg8]);
                half8 kl8 = *reinterpret_cast<const half8*>(&Ks_l[fc * 16 + ml][gch * 32 + kg8]);
                s0 = MFMA16(qh_[gch], kh8, s0);
                sL = MFMA16(qh_[gch], kl8, sL);
                sL = MFMA16(ql_[gch], kh8, sL);
            }
            int mv = mb[kt * 64 + fc * 16 + ml];   // mask for this lane's k-col
            #pragma unroll
            for (int r = 0; r < 4; ++r) {
                float sv = s0[r] + sL[r] * (1.0f / 2048.0f);
                sv = floorf(sv * 0.125f);
                if (mv == 0) sv = -INFINITY;
                Ss[w][(lane >> 4) * 4 + r][fc * 16 + ml] = (_Float16)sv;
            }
        }

        // --- S @ V ---
        half8 sa[2];
        #pragma unroll
        for (int sg = 0; sg < 2; ++sg)
            sa[sg] = *reinterpret_cast<const half8*>(&Ss[w][ml][sg * 32 + kg8]);
        #pragma unroll
        for (int f = 0; f < 4; ++f) {
            #pragma unroll
            for (int sg = 0; sg < 2; ++sg) {
                half8 vb8 = *reinterpret_cast<const half8*>(&Vs[f * 16 + ml][sg * 32 + kg8]);
                oacc[f] = MFMA16(sa[sg], vb8, oacc[f]);
            }
        }
    }

    // epilogue
    #pragma unroll
    for (int f = 0; f < 4; ++f) {
        #pragma unroll
        for (int reg = 0; reg < 4; ++reg) {
            int row = b * SS + qt * 64 + w * 16 + (lane >> 4) * 4 + reg;
            out[(size_t)row * HIDDEN + h * HDIM + f * 16 + ml] = oacc[f][reg];
        }
    }
}

extern "C" void kernel_launch(void* const* d_in, const int* in_sizes, int n_in,
                              void* d_out, int out_size, void* d_ws, size_t ws_size,
                              hipStream_t stream) {
    (void)in_sizes; (void)n_in; (void)out_size; (void)ws_size;
    const float* x    = (const float*)d_in[0];
    const int*   mask = (const int*)d_in[1];
    const float* Wq   = (const float*)d_in[2];
    const float* bq   = (const float*)d_in[3];
    const float* Wk   = (const float*)d_in[4];
    const float* bk   = (const float*)d_in[5];
    const float* Wv   = (const float*)d_in[6];
    const float* bv   = (const float*)d_in[7];
    float* out = (float*)d_out;

    float* qbuf = (float*)d_ws;                         // 4096*2048 f32 = 32 MB
    float* kbuf = qbuf + (size_t)BB * SS * HIDDEN;      // 4096*512  f32 =  8 MB
    float* vbuf = kbuf + (size_t)BB * SS * KVDIM;       // 4096*512  f32 =  8 MB

    const int M = BB * SS;
    gemm_split<<<dim3(M / 128, HIDDEN / 128), 256, 0, stream>>>(x, Wq, bq, qbuf, M, HIDDEN, HIDDEN);
    gemm_split<<<dim3(M / 128, KVDIM / 128), 256, 0, stream>>>(x, Wk, bk, kbuf, M, KVDIM, HIDDEN);
    gemm_split<<<dim3(M / 128, KVDIM / 128), 256, 0, stream>>>(x, Wv, bv, vbuf, M, KVDIM, HIDDEN);
    attn_mfma<<<dim3(SS / 64, BB * NHEADS), 256, 0, stream>>>(qbuf, kbuf, vbuf, mask, out);
}

// Round 3
// 336.844 us; speedup vs baseline: 6.4917x; 2.8078x over previous
//
#include <hip/hip_runtime.h>
#include <math.h>

#define HIDDEN 2048
#define NHEADS 32
#define HDIM 64
#define GNUM 8
#define KVDIM 512
#define BB 2
#define SS 2048
#define MROWS (BB * SS)   // 4096
#define NQKV 3072

typedef _Float16 half8 __attribute__((ext_vector_type(8)));
typedef _Float16 half4 __attribute__((ext_vector_type(4)));
typedef _Float16 half2 __attribute__((ext_vector_type(2)));
typedef float floatx4 __attribute__((ext_vector_type(4)));

#define MFMA16(a, b, c) __builtin_amdgcn_mfma_f32_16x16x32_f16((a), (b), (c), 0, 0, 0)

// split x = hi + (lo/2048), lo scaled into fp16 normal range
__device__ __forceinline__ void split_f32(float x, _Float16& hi, _Float16& lo) {
    hi = (_Float16)x;
    lo = (_Float16)((x - (float)hi) * 2048.0f);
}

__device__ __forceinline__ void load_lds16(const void* g, void* l) {
    __builtin_amdgcn_global_load_lds(
        (const __attribute__((address_space(1))) void*)g,
        (__attribute__((address_space(3))) void*)l, 16, 0, 0);
}

// ---------------------------------------------------------------------------
// x [4096][2048] f32 -> xh, xl fp16
// ---------------------------------------------------------------------------
__global__ __launch_bounds__(256)
void split_x(const float* __restrict__ x, _Float16* __restrict__ xh,
             _Float16* __restrict__ xl, int n4) {
    for (int idx = blockIdx.x * 256 + threadIdx.x; idx < n4; idx += gridDim.x * 256) {
        floatx4 v = reinterpret_cast<const floatx4*>(x)[idx];
        half4 h, l;
        #pragma unroll
        for (int e = 0; e < 4; ++e) { _Float16 hi, lo; split_f32(v[e], hi, lo); h[e] = hi; l[e] = lo; }
        reinterpret_cast<half4*>(xh)[idx] = h;
        reinterpret_cast<half4*>(xl)[idx] = l;
    }
}

// ---------------------------------------------------------------------------
// W [2048][N] f32 -> Wt rows [n0 .. n0+N) of [NQKV][2048] fp16 hi/lo (transposed)
// ---------------------------------------------------------------------------
__global__ __launch_bounds__(256)
void split_wt(const float* __restrict__ W, int N, int n0,
              _Float16* __restrict__ Wth, _Float16* __restrict__ Wtl) {
    __shared__ float tile[64][68];
    const int tid = threadIdx.x;
    const int kb = blockIdx.x, nb = blockIdx.y;
    #pragma unroll
    for (int i = 0; i < 4; ++i) {
        int idx = tid + i * 256;           // 64 rows x 16 float4
        int r = idx >> 4, c4 = idx & 15;
        floatx4 v = *reinterpret_cast<const floatx4*>(&W[(size_t)(kb * 64 + r) * N + nb * 64 + c4 * 4]);
        *reinterpret_cast<floatx4*>(&tile[r][c4 * 4]) = v;
    }
    __syncthreads();
    #pragma unroll
    for (int i = 0; i < 4; ++i) {
        int idx = tid + i * 256;
        int r2 = idx >> 4, c2 = (idx & 15) * 4;   // r2 = local n, c2 = local k
        half4 h, l;
        #pragma unroll
        for (int e = 0; e < 4; ++e) {
            _Float16 hi, lo;
            split_f32(tile[c2 + e][r2], hi, lo);
            h[e] = hi; l[e] = lo;
        }
        size_t o = (size_t)(n0 + nb * 64 + r2) * HIDDEN + kb * 64 + c2;
        *reinterpret_cast<half4*>(&Wth[o]) = h;
        *reinterpret_cast<half4*>(&Wtl[o]) = l;
    }
}

__global__ __launch_bounds__(256)
void biascat_k(const float* __restrict__ bq, const float* __restrict__ bk,
               const float* __restrict__ bv, float* __restrict__ bias) {
    int i = blockIdx.x * 256 + threadIdx.x;
    if (i < 2048) bias[i] = bq[i];
    else if (i < 2560) bias[i] = bk[i - 2048];
    else if (i < NQKV) bias[i] = bv[i - 2560];
}

// ---------------------------------------------------------------------------
// Unified QKV GEMM: [4096][2048] @ [2048][3072] + bias, split-fp16 3-term.
// 128x128 tile, BK=64, 4 waves; global_load_lds w/ pre-swizzled source;
// epilogue: cols <2048 -> qh/ql fp16; <2560 -> kh/kl; else vh.
// ---------------------------------------------------------------------------
__global__ __launch_bounds__(256, 2)
void gemm_qkv(const _Float16* __restrict__ xh, const _Float16* __restrict__ xl,
              const _Float16* __restrict__ Wth, const _Float16* __restrict__ Wtl,
              const float* __restrict__ bias,
              _Float16* __restrict__ qh, _Float16* __restrict__ ql,
              _Float16* __restrict__ kh, _Float16* __restrict__ kl,
              _Float16* __restrict__ vh) {
    __shared__ __align__(16) _Float16 Ah[128 * 64];
    __shared__ __align__(16) _Float16 Al[128 * 64];
    __shared__ __align__(16) _Float16 Bh[128 * 64];
    __shared__ __align__(16) _Float16 Bl[128 * 64];

    const int tid  = threadIdx.x;
    const int lane = tid & 63;
    const int w    = tid >> 6;
    const int wm   = w >> 1, wn = w & 1;
    const int bm   = blockIdx.x, bn = blockIdx.y;
    const int ml   = lane & 15;
    const int kg8  = (lane >> 4) * 8;

    const _Float16* gsrc;
    _Float16* ldst;
    if      (w == 0) { gsrc = xh  + (size_t)(bm * 128) * HIDDEN; ldst = Ah; }
    else if (w == 1) { gsrc = xl  + (size_t)(bm * 128) * HIDDEN; ldst = Al; }
    else if (w == 2) { gsrc = Wth + (size_t)(bn * 128) * HIDDEN; ldst = Bh; }
    else             { gsrc = Wtl + (size_t)(bn * 128) * HIDDEN; ldst = Bl; }

    floatx4 acc0[4][4] = {};
    floatx4 accL[4][4] = {};

    for (int k0 = 0; k0 < HIDDEN; k0 += 64) {
        // stage: wave w fills its buffer; linear LDS dest, swizzled global src
        #pragma unroll
        for (int i = 0; i < 16; ++i) {
            int L   = i * 1024 + lane * 16;            // linear LDS byte
            int row = L >> 7;                          // 128 B rows
            int off = (L & 127) ^ ((row & 7) << 4);    // inverse-swizzled src byte
            const void* gp = (const char*)(gsrc + (size_t)row * HIDDEN + k0) + off;
            void* lp = (char*)ldst + i * 1024;
            load_lds16(gp, lp);
        }
        __syncthreads();

        #pragma unroll
        for (int kc = 0; kc < 2; ++kc) {
            half8 a_h[4], a_l[4], b_h[4], b_l[4];
            #pragma unroll
            for (int r = 0; r < 4; ++r) {
                int row = wm * 64 + r * 16 + ml;
                int byt = row * 128 + (((kc * 64 + kg8 * 2)) ^ ((row & 7) << 4));
                a_h[r] = *reinterpret_cast<const half8*>((const char*)Ah + byt);
                a_l[r] = *reinterpret_cast<const half8*>((const char*)Al + byt);
            }
            #pragma unroll
            for (int c = 0; c < 4; ++c) {
                int row = wn * 64 + c * 16 + ml;
                int byt = row * 128 + (((kc * 64 + kg8 * 2)) ^ ((row & 7) << 4));
                b_h[c] = *reinterpret_cast<const half8*>((const char*)Bh + byt);
                b_l[c] = *reinterpret_cast<const half8*>((const char*)Bl + byt);
            }
            #pragma unroll
            for (int r = 0; r < 4; ++r)
                #pragma unroll
                for (int c = 0; c < 4; ++c) {
                    acc0[r][c] = MFMA16(a_h[r], b_h[c], acc0[r][c]);
                    accL[r][c] = MFMA16(a_h[r], b_l[c], accL[r][c]);
                    accL[r][c] = MFMA16(a_l[r], b_h[c], accL[r][c]);
                }
        }
        __syncthreads();
    }

    // epilogue
    #pragma unroll
    for (int c = 0; c < 4; ++c) {
        int colg = bn * 128 + wn * 64 + c * 16 + ml;
        float bval = bias[colg];
        #pragma unroll
        for (int r = 0; r < 4; ++r) {
            int rowg = bm * 128 + wm * 64 + r * 16 + (lane >> 4) * 4;
            #pragma unroll
            for (int reg = 0; reg < 4; ++reg) {
                float val = acc0[r][c][reg] + accL[r][c][reg] * (1.0f / 2048.0f) + bval;
                int rr = rowg + reg;
                if (colg < 2048) {
                    _Float16 hi, lo; split_f32(val, hi, lo);
                    qh[(size_t)rr * HIDDEN + colg] = hi;
                    ql[(size_t)rr * HIDDEN + colg] = lo;
                } else if (colg < 2560) {
                    int ck = colg - 2048;
                    _Float16 hi, lo; split_f32(val, hi, lo);
                    kh[(size_t)rr * KVDIM + ck] = hi;
                    kl[(size_t)rr * KVDIM + ck] = lo;
                } else {
                    vh[(size_t)rr * KVDIM + (colg - 2560)] = (_Float16)val;
                }
            }
        }
    }
}

// ---------------------------------------------------------------------------
// Fused attention: block = (b, g, 64 q-rows) x 4 heads sharing K/V staging.
// 4 waves; wave owns 16 q-rows for all 4 heads. out = floor(QK^T/8,mask) @ V.
// ---------------------------------------------------------------------------
__global__ __launch_bounds__(256, 2)
void attn4(const _Float16* __restrict__ qh, const _Float16* __restrict__ ql,
           const _Float16* __restrict__ kh, const _Float16* __restrict__ kl,
           const _Float16* __restrict__ vh, const int* __restrict__ mask,
           float* __restrict__ out) {
    __shared__ __align__(16) _Float16 Ksh[64][72];
    __shared__ __align__(16) _Float16 Ksl[64][72];
    __shared__ __align__(16) _Float16 Vst[64][72];      // transposed [dim][k]
    __shared__ __align__(16) _Float16 Ss[4][4][16][72]; // [wave][head][row][col]

    const int tid  = threadIdx.x;
    const int lane = tid & 63;
    const int w    = tid >> 6;
    const int ml   = lane & 15;
    const int kg8  = (lane >> 4) * 8;
    const int qt   = blockIdx.x;
    const int b    = blockIdx.y >> 3, g = blockIdx.y & 7;

    // hoist Q fragments: 16 rows (this wave) x 4 heads, hi/lo
    half8 qhf[4][2], qlf[4][2];
    {
        size_t rowbase = (size_t)(b * SS + qt * 64 + w * 16 + ml) * HIDDEN;
        #pragma unroll
        for (int hh = 0; hh < 4; ++hh) {
            int hcol = (g * 4 + hh) * HDIM;
            #pragma unroll
            for (int gch = 0; gch < 2; ++gch) {
                qhf[hh][gch] = *reinterpret_cast<const half8*>(&qh[rowbase + hcol + gch * 32 + kg8]);
                qlf[hh][gch] = *reinterpret_cast<const half8*>(&ql[rowbase + hcol + gch * 32 + kg8]);
            }
        }
    }

    const _Float16* khg = kh + (size_t)b * SS * KVDIM + g * HDIM;
    const _Float16* klg = kl + (size_t)b * SS * KVDIM + g * HDIM;
    const _Float16* vhg = vh + (size_t)b * SS * KVDIM + g * HDIM;
    const int* mb = mask + b * SS;

    floatx4 oacc[4][4] = {};   // [head][dim-frag]

    for (int kt = 0; kt < SS / 64; ++kt) {
        __syncthreads();   // previous tile fully consumed
        // stage K hi/lo (copy)
        #pragma unroll
        for (int i = 0; i < 2; ++i) {
            int idx = tid + i * 256;          // 64 rows x 8 chunks
            int kk = idx >> 3, d8 = (idx & 7) * 8;
            *reinterpret_cast<half8*>(&Ksh[kk][d8]) =
                *reinterpret_cast<const half8*>(&khg[(size_t)(kt * 64 + kk) * KVDIM + d8]);
            *reinterpret_cast<half8*>(&Ksl[kk][d8]) =
                *reinterpret_cast<const half8*>(&klg[(size_t)(kt * 64 + kk) * KVDIM + d8]);
        }
        // stage V transposed
        {
            int rp = (tid & 31) * 2, c8 = (tid >> 5) * 8;
            half8 v0 = *reinterpret_cast<const half8*>(&vhg[(size_t)(kt * 64 + rp) * KVDIM + c8]);
            half8 v1 = *reinterpret_cast<const half8*>(&vhg[(size_t)(kt * 64 + rp + 1) * KVDIM + c8]);
            #pragma unroll
            for (int e = 0; e < 8; ++e)
                *reinterpret_cast<half2*>(&Vst[c8 + e][rp]) = half2{v0[e], v1[e]};
        }
        __syncthreads();

        int mv[4];
        #pragma unroll
        for (int fc = 0; fc < 4; ++fc) mv[fc] = mb[kt * 64 + fc * 16 + ml];

        // QK^T: K-frags hoisted across the 4 heads
        #pragma unroll
        for (int fc = 0; fc < 4; ++fc) {
            half8 k_h[2], k_l[2];
            #pragma unroll
            for (int gch = 0; gch < 2; ++gch) {
                k_h[gch] = *reinterpret_cast<const half8*>(&Ksh[fc * 16 + ml][gch * 32 + kg8]);
                k_l[gch] = *reinterpret_cast<const half8*>(&Ksl[fc * 16 + ml][gch * 32 + kg8]);
            }
            #pragma unroll
            for (int hh = 0; hh < 4; ++hh) {
                floatx4 s0 = {}, sL = {};
                #pragma unroll
                for (int gch = 0; gch < 2; ++gch) {
                    s0 = MFMA16(qhf[hh][gch], k_h[gch], s0);
                    sL = MFMA16(qhf[hh][gch], k_l[gch], sL);
                    sL = MFMA16(qlf[hh][gch], k_h[gch], sL);
                }
                #pragma unroll
                for (int r = 0; r < 4; ++r) {
                    float sv = s0[r] + sL[r] * (1.0f / 2048.0f);
                    sv = floorf(sv * 0.125f);
                    if (mv[fc] == 0) sv = -INFINITY;
                    Ss[w][hh][(lane >> 4) * 4 + r][fc * 16 + ml] = (_Float16)sv;
                }
            }
        }

        // S @ V: V-frags hoisted across heads
        half8 sa[4][2];
        #pragma unroll
        for (int hh = 0; hh < 4; ++hh)
            #pragma unroll
            for (int sg = 0; sg < 2; ++sg)
                sa[hh][sg] = *reinterpret_cast<const half8*>(&Ss[w][hh][ml][sg * 32 + kg8]);
        #pragma unroll
        for (int f = 0; f < 4; ++f) {
            half8 vb0 = *reinterpret_cast<const half8*>(&Vst[f * 16 + ml][kg8]);
            half8 vb1 = *reinterpret_cast<const half8*>(&Vst[f * 16 + ml][32 + kg8]);
            #pragma unroll
            for (int hh = 0; hh < 4; ++hh) {
                oacc[hh][f] = MFMA16(sa[hh][0], vb0, oacc[hh][f]);
                oacc[hh][f] = MFMA16(sa[hh][1], vb1, oacc[hh][f]);
            }
        }
    }

    // epilogue
    #pragma unroll
    for (int hh = 0; hh < 4; ++hh) {
        int hcol = (g * 4 + hh) * HDIM;
        #pragma unroll
        for (int f = 0; f < 4; ++f)
            #pragma unroll
            for (int reg = 0; reg < 4; ++reg) {
                int row = b * SS + qt * 64 + w * 16 + (lane >> 4) * 4 + reg;
                out[(size_t)row * HIDDEN + hcol + f * 16 + ml] = oacc[hh][f][reg];
            }
    }
}

extern "C" void kernel_launch(void* const* d_in, const int* in_sizes, int n_in,
                              void* d_out, int out_size, void* d_ws, size_t ws_size,
                              hipStream_t stream) {
    (void)in_sizes; (void)n_in; (void)out_size; (void)ws_size;
    const float* x    = (const float*)d_in[0];
    const int*   mask = (const int*)d_in[1];
    const float* Wq   = (const float*)d_in[2];
    const float* bq   = (const float*)d_in[3];
    const float* Wk   = (const float*)d_in[4];
    const float* bk   = (const float*)d_in[5];
    const float* Wv   = (const float*)d_in[6];
    const float* bv   = (const float*)d_in[7];

    _Float16* ws16 = (_Float16*)d_ws;
    size_t o = 0;
    auto alloc16 = [&](size_t n) { _Float16* p = ws16 + o; o += n; return p; };
    _Float16* xh  = alloc16((size_t)MROWS * HIDDEN);   // 8.4M halves
    _Float16* xl  = alloc16((size_t)MROWS * HIDDEN);
    _Float16* Wth = alloc16((size_t)NQKV * HIDDEN);    // 6.3M
    _Float16* Wtl = alloc16((size_t)NQKV * HIDDEN);
    _Float16* qh  = alloc16((size_t)MROWS * HIDDEN);
    _Float16* ql  = alloc16((size_t)MROWS * HIDDEN);
    _Float16* kh  = alloc16((size_t)MROWS * KVDIM);
    _Float16* kl  = alloc16((size_t)MROWS * KVDIM);
    _Float16* vh  = alloc16((size_t)MROWS * KVDIM);
    float* biascat = (float*)(ws16 + o);               // 3072 f32

    split_x<<<2048, 256, 0, stream>>>(x, xh, xl, MROWS * HIDDEN / 4);
    split_wt<<<dim3(32, 32), 256, 0, stream>>>(Wq, HIDDEN, 0,    Wth, Wtl);
    split_wt<<<dim3(32, 8),  256, 0, stream>>>(Wk, KVDIM, 2048, Wth, Wtl);
    split_wt<<<dim3(32, 8),  256, 0, stream>>>(Wv, KVDIM, 2560, Wth, Wtl);
    biascat_k<<<12, 256, 0, stream>>>(bq, bk, bv, biascat);
    gemm_qkv<<<dim3(MROWS / 128, NQKV / 128), 256, 0, stream>>>(
        xh, xl, Wth, Wtl, biascat, qh, ql, kh, kl, vh);
    attn4<<<dim3(SS / 64, BB * GNUM), 256, 0, stream>>>(qh, ql, kh, kl, vh, mask, (float*)d_out);
}

// Round 5
// 305.585 us; speedup vs baseline: 7.1557x; 1.1023x over previous
//
#include <hip/hip_runtime.h>
#include <math.h>

#define HIDDEN 2048
#define NHEADS 32
#define HDIM 64
#define GNUM 8
#define KVDIM 512
#define BB 2
#define SS 2048
#define MROWS (BB * SS)   // 4096
#define NQKV 3072

typedef _Float16 half8 __attribute__((ext_vector_type(8)));
typedef _Float16 half4 __attribute__((ext_vector_type(4)));
typedef _Float16 half2 __attribute__((ext_vector_type(2)));
typedef __fp16 fp16x2 __attribute__((ext_vector_type(2)));
typedef float floatx4 __attribute__((ext_vector_type(4)));

#define MFMA16(a, b, c) __builtin_amdgcn_mfma_f32_16x16x32_f16((a), (b), (c), 0, 0, 0)

// split x = hi + (lo/2048), lo scaled into fp16 normal range
__device__ __forceinline__ void split_f32(float x, _Float16& hi, _Float16& lo) {
    hi = (_Float16)x;
    lo = (_Float16)((x - (float)hi) * 2048.0f);
}

__device__ __forceinline__ void load_lds16(const void* g, void* l) {
    __builtin_amdgcn_global_load_lds(
        (const __attribute__((address_space(1))) void*)g,
        (__attribute__((address_space(3))) void*)l, 16, 0, 0);
}

// permlane swaps (gfx950): exchange 32-lane halves / odd-even 16-rows of two VGPRs
__device__ __forceinline__ void permswap32(unsigned& a, unsigned& b) {
    asm volatile("v_permlane32_swap_b32 %0, %1" : "+v"(a), "+v"(b));
}
__device__ __forceinline__ void permswap16(unsigned& a, unsigned& b) {
    asm volatile("v_permlane16_swap_b32 %0, %1" : "+v"(a), "+v"(b));
}

__device__ __forceinline__ unsigned pk_f16(float a, float b) {
    union { fp16x2 h; unsigned u; } c;
    c.h = __builtin_amdgcn_cvt_pkrtz(a, b);
    return c.u;
}

// ---------------------------------------------------------------------------
// x [4096][2048] f32 -> xh, xl fp16
// ---------------------------------------------------------------------------
__global__ __launch_bounds__(256)
void split_x(const float* __restrict__ x, _Float16* __restrict__ xh,
             _Float16* __restrict__ xl, int n4) {
    for (int idx = blockIdx.x * 256 + threadIdx.x; idx < n4; idx += gridDim.x * 256) {
        floatx4 v = reinterpret_cast<const floatx4*>(x)[idx];
        half4 h, l;
        #pragma unroll
        for (int e = 0; e < 4; ++e) { _Float16 hi, lo; split_f32(v[e], hi, lo); h[e] = hi; l[e] = lo; }
        reinterpret_cast<half4*>(xh)[idx] = h;
        reinterpret_cast<half4*>(xl)[idx] = l;
    }
}

// ---------------------------------------------------------------------------
// W [2048][N] f32 -> Wt rows [n0 .. n0+N) of [NQKV][2048] fp16 hi/lo (transposed)
// ---------------------------------------------------------------------------
__global__ __launch_bounds__(256)
void split_wt(const float* __restrict__ W, int N, int n0,
              _Float16* __restrict__ Wth, _Float16* __restrict__ Wtl) {
    __shared__ float tile[64][68];
    const int tid = threadIdx.x;
    const int kb = blockIdx.x, nb = blockIdx.y;
    #pragma unroll
    for (int i = 0; i < 4; ++i) {
        int idx = tid + i * 256;           // 64 rows x 16 float4
        int r = idx >> 4, c4 = idx & 15;
        floatx4 v = *reinterpret_cast<const floatx4*>(&W[(size_t)(kb * 64 + r) * N + nb * 64 + c4 * 4]);
        *reinterpret_cast<floatx4*>(&tile[r][c4 * 4]) = v;
    }
    __syncthreads();
    #pragma unroll
    for (int i = 0; i < 4; ++i) {
        int idx = tid + i * 256;
        int r2 = idx >> 4, c2 = (idx & 15) * 4;   // r2 = local n, c2 = local k
        half4 h, l;
        #pragma unroll
        for (int e = 0; e < 4; ++e) {
            _Float16 hi, lo;
            split_f32(tile[c2 + e][r2], hi, lo);
            h[e] = hi; l[e] = lo;
        }
        size_t o = (size_t)(n0 + nb * 64 + r2) * HIDDEN + kb * 64 + c2;
        *reinterpret_cast<half4*>(&Wth[o]) = h;
        *reinterpret_cast<half4*>(&Wtl[o]) = l;
    }
}

__global__ __launch_bounds__(256)
void biascat_k(const float* __restrict__ bq, const float* __restrict__ bk,
               const float* __restrict__ bv, float* __restrict__ bias) {
    int i = blockIdx.x * 256 + threadIdx.x;
    if (i < 2048) bias[i] = bq[i];
    else if (i < 2560) bias[i] = bk[i - 2048];
    else if (i < NQKV) bias[i] = bv[i - 2560];
}

// ---------------------------------------------------------------------------
// Unified QKV GEMM: [4096][2048] @ [2048][3072] + bias, split-fp16 3-term.
// K output written into per-(b,g) tiled + XOR-swizzled layout for attn's
// global_load_lds staging (rule #21: swizzle source + read, linear LDS dest).
// ---------------------------------------------------------------------------
__global__ __launch_bounds__(256, 2)
void gemm_qkv(const _Float16* __restrict__ xh, const _Float16* __restrict__ xl,
              const _Float16* __restrict__ Wth, const _Float16* __restrict__ Wtl,
              const float* __restrict__ bias,
              _Float16* __restrict__ qh, _Float16* __restrict__ ql,
              _Float16* __restrict__ khs, _Float16* __restrict__ kls,
              _Float16* __restrict__ vh) {
    __shared__ __align__(16) _Float16 Ah[128 * 64];
    __shared__ __align__(16) _Float16 Al[128 * 64];
    __shared__ __align__(16) _Float16 Bh[128 * 64];
    __shared__ __align__(16) _Float16 Bl[128 * 64];

    const int tid  = threadIdx.x;
    const int lane = tid & 63;
    const int w    = tid >> 6;
    const int wm   = w >> 1, wn = w & 1;
    const int bm   = blockIdx.x, bn = blockIdx.y;
    const int ml   = lane & 15;
    const int kg8  = (lane >> 4) * 8;

    const _Float16* gsrc;
    _Float16* ldst;
    if      (w == 0) { gsrc = xh  + (size_t)(bm * 128) * HIDDEN; ldst = Ah; }
    else if (w == 1) { gsrc = xl  + (size_t)(bm * 128) * HIDDEN; ldst = Al; }
    else if (w == 2) { gsrc = Wth + (size_t)(bn * 128) * HIDDEN; ldst = Bh; }
    else             { gsrc = Wtl + (size_t)(bn * 128) * HIDDEN; ldst = Bl; }

    floatx4 acc0[4][4] = {};
    floatx4 accL[4][4] = {};

    for (int k0 = 0; k0 < HIDDEN; k0 += 64) {
        #pragma unroll
        for (int i = 0; i < 16; ++i) {
            int L   = i * 1024 + lane * 16;            // linear LDS byte
            int row = L >> 7;                          // 128 B rows
            int off = (L & 127) ^ ((row & 7) << 4);    // inverse-swizzled src byte
            const void* gp = (const char*)(gsrc + (size_t)row * HIDDEN + k0) + off;
            void* lp = (char*)ldst + i * 1024;
            load_lds16(gp, lp);
        }
        __syncthreads();

        #pragma unroll
        for (int kc = 0; kc < 2; ++kc) {
            half8 a_h[4], a_l[4], b_h[4], b_l[4];
            #pragma unroll
            for (int r = 0; r < 4; ++r) {
                int row = wm * 64 + r * 16 + ml;
                int byt = row * 128 + (((kc * 64 + kg8 * 2)) ^ ((row & 7) << 4));
                a_h[r] = *reinterpret_cast<const half8*>((const char*)Ah + byt);
                a_l[r] = *reinterpret_cast<const half8*>((const char*)Al + byt);
            }
            #pragma unroll
            for (int c = 0; c < 4; ++c) {
                int row = wn * 64 + c * 16 + ml;
                int byt = row * 128 + (((kc * 64 + kg8 * 2)) ^ ((row & 7) << 4));
                b_h[c] = *reinterpret_cast<const half8*>((const char*)Bh + byt);
                b_l[c] = *reinterpret_cast<const half8*>((const char*)Bl + byt);
            }
            #pragma unroll
            for (int r = 0; r < 4; ++r)
                #pragma unroll
                for (int c = 0; c < 4; ++c) {
                    acc0[r][c] = MFMA16(a_h[r], b_h[c], acc0[r][c]);
                    accL[r][c] = MFMA16(a_h[r], b_l[c], accL[r][c]);
                    accL[r][c] = MFMA16(a_l[r], b_h[c], accL[r][c]);
                }
        }
        __syncthreads();
    }

    // epilogue
    #pragma unroll
    for (int c = 0; c < 4; ++c) {
        int colg = bn * 128 + wn * 64 + c * 16 + ml;
        float bval = bias[colg];
        #pragma unroll
        for (int r = 0; r < 4; ++r) {
            int rowg = bm * 128 + wm * 64 + r * 16 + (lane >> 4) * 4;
            #pragma unroll
            for (int reg = 0; reg < 4; ++reg) {
                float val = acc0[r][c][reg] + accL[r][c][reg] * (1.0f / 2048.0f) + bval;
                int rr = rowg + reg;
                if (colg < 2048) {
                    _Float16 hi, lo; split_f32(val, hi, lo);
                    qh[(size_t)rr * HIDDEN + colg] = hi;
                    ql[(size_t)rr * HIDDEN + colg] = lo;
                } else if (colg < 2560) {
                    int ck = colg - 2048;
                    int gk = ck >> 6, dk = ck & 63;
                    int bk_ = rr >> 11, sk_ = rr & 2047;
                    int kk = sk_ & 63;
                    size_t baseK = ((size_t)((bk_ * 8 + gk) * 32 + (sk_ >> 6))) * 4096
                                 + kk * 64 + (dk ^ ((kk & 7) << 3));
                    _Float16 hi, lo; split_f32(val, hi, lo);
                    khs[baseK] = hi;
                    kls[baseK] = lo;
                } else {
                    vh[(size_t)rr * KVDIM + (colg - 2560)] = (_Float16)val;
                }
            }
        }
    }
}

// ---------------------------------------------------------------------------
// Fused attention, in-register scores:
//   S^T = mfma(K,Q); floor/mask in regs; permlane32+16 swap -> SV B-frags;
//   out^T = mfma(V^T, S^T).  Block = (b, g, 64 q-rows), 4 heads share K/V.
// ---------------------------------------------------------------------------
__global__ __launch_bounds__(256, 2)
void attn5(const _Float16* __restrict__ qh, const _Float16* __restrict__ ql,
           const _Float16* __restrict__ khs, const _Float16* __restrict__ kls,
           const _Float16* __restrict__ vh, const int* __restrict__ mask,
           float* __restrict__ out) {
    __shared__ __align__(16) _Float16 Ksh[64 * 64];   // linear, XOR-swizzled content
    __shared__ __align__(16) _Float16 Ksl[64 * 64];
    __shared__ __align__(16) _Float16 Vst[64][72];    // transposed [dim][k]

    const int tid  = threadIdx.x;
    const int lane = tid & 63;
    const int w    = tid >> 6;
    const int ml   = lane & 15;
    const int lg   = lane >> 4;
    const int kg8  = lg * 8;

    // XCD-aware remap: all 32 q-tiles of one (b,g) on the same XCD
    const int f_  = blockIdx.y * 32 + blockIdx.x;      // 0..511
    const int bg  = (f_ & 7) | ((f_ >> 8) << 3);
    const int qt  = (f_ >> 3) & 31;
    const int b   = bg >> 3, g = bg & 7;

    // hoist Q fragments (16 rows this wave, 4 heads), pre-scaled by 1/8 (exact)
    half8 qhf[4][2], qlf[4][2];
    {
        size_t rowbase = (size_t)(b * SS + qt * 64 + w * 16 + ml) * HIDDEN;
        #pragma unroll
        for (int hh = 0; hh < 4; ++hh) {
            int hcol = (g * 4 + hh) * HDIM;
            #pragma unroll
            for (int gch = 0; gch < 2; ++gch) {
                half8 a = *reinterpret_cast<const half8*>(&qh[rowbase + hcol + gch * 32 + kg8]);
                half8 c = *reinterpret_cast<const half8*>(&ql[rowbase + hcol + gch * 32 + kg8]);
                qhf[hh][gch] = a * (_Float16)0.125f;
                qlf[hh][gch] = c * (_Float16)0.125f;
            }
        }
    }

    const _Float16* ktile_h = khs + (size_t)(bg * 32) * 4096;
    const _Float16* ktile_l = kls + (size_t)(bg * 32) * 4096;
    const _Float16* vbg = vh + (size_t)b * SS * KVDIM + g * HDIM;
    const int* mb = mask + b * SS;

    floatx4 oacc[4][4] = {};   // [head][dim-frag]; col=q, row=d

    for (int kt = 0; kt < SS / 64; ++kt) {
        __syncthreads();   // previous tile fully consumed
        if (w == 0) {
            #pragma unroll
            for (int j = 0; j < 8; ++j)
                load_lds16((const char*)(ktile_h + (size_t)kt * 4096) + j * 1024 + lane * 16,
                           (char*)Ksh + j * 1024);
        } else if (w == 1) {
            #pragma unroll
            for (int j = 0; j < 8; ++j)
                load_lds16((const char*)(ktile_l + (size_t)kt * 4096) + j * 1024 + lane * 16,
                           (char*)Ksl + j * 1024);
        }
        // V transpose staging (all threads)
        {
            int rp = (tid & 31) * 2, c8 = (tid >> 5) * 8;
            half8 v0 = *reinterpret_cast<const half8*>(&vbg[(size_t)(kt * 64 + rp) * KVDIM + c8]);
            half8 v1 = *reinterpret_cast<const half8*>(&vbg[(size_t)(kt * 64 + rp + 1) * KVDIM + c8]);
            #pragma unroll
            for (int e = 0; e < 8; ++e)
                *reinterpret_cast<half2*>(&Vst[c8 + e][rp]) = half2{v0[e], v1[e]};
        }
        __syncthreads();

        // hoist V^T fragments (shared across heads)
        half8 av[4][2];
        #pragma unroll
        for (int f = 0; f < 4; ++f)
            #pragma unroll
            for (int kc = 0; kc < 2; ++kc)
                av[f][kc] = *reinterpret_cast<const half8*>(&Vst[f * 16 + ml][kc * 32 + kg8]);

        int4 m4v[4];
        #pragma unroll
        for (int fc = 0; fc < 4; ++fc)
            m4v[fc] = *reinterpret_cast<const int4*>(&mb[kt * 64 + fc * 16 + lg * 4]);

        __builtin_amdgcn_s_setprio(1);

        // QK^T (swapped): per fc read K-frags once, all 4 heads consume
        unsigned h2[4][4][2];   // [hh][fc][p] packed fp16 score pairs
        #pragma unroll
        for (int fc = 0; fc < 4; ++fc) {
            int krow = fc * 16 + ml;
            int xo = (krow & 7) << 3;
            half8 k_h[2], k_l[2];
            #pragma unroll
            for (int gch = 0; gch < 2; ++gch) {
                k_h[gch] = *reinterpret_cast<const half8*>(&Ksh[krow * 64 + ((gch * 32 + kg8) ^ xo)]);
                k_l[gch] = *reinterpret_cast<const half8*>(&Ksl[krow * 64 + ((gch * 32 + kg8) ^ xo)]);
            }
            #pragma unroll
            for (int hh = 0; hh < 4; ++hh) {
                floatx4 s0 = {}, sl = {};
                s0 = MFMA16(k_h[0], qhf[hh][0], s0);
                s0 = MFMA16(k_h[1], qhf[hh][1], s0);
                sl = MFMA16(k_l[0], qhf[hh][0], sl);
                sl = MFMA16(k_l[1], qhf[hh][1], sl);
                sl = MFMA16(k_h[0], qlf[hh][0], sl);
                sl = MFMA16(k_h[1], qlf[hh][1], sl);
                float sv[4];
                #pragma unroll
                for (int r = 0; r < 4; ++r) {
                    float t = floorf(fmaf(sl[r], 1.0f / 2048.0f, s0[r]));
                    sv[r] = (m4v[fc][r] == 0) ? -INFINITY : t;
                }
                h2[hh][fc][0] = pk_f16(sv[0], sv[1]);
                h2[hh][fc][1] = pk_f16(sv[2], sv[3]);
            }
        }

        // S @ V via out^T = mfma(V^T-frag, S^T-B-frag built by permlane swaps)
        #pragma unroll
        for (int hh = 0; hh < 4; ++hh) {
            #pragma unroll
            for (int kc = 0; kc < 2; ++kc) {
                unsigned t0 = h2[hh][2 * kc][0], tA = h2[hh][2 * kc + 1][0];
                unsigned t1 = h2[hh][2 * kc][1], tB = h2[hh][2 * kc + 1][1];
                permswap32(t0, tA); permswap16(t0, tA);
                permswap32(t1, tB); permswap16(t1, tB);
                union { unsigned u[4]; half8 h; } bu;
                bu.u[0] = t0; bu.u[1] = t1; bu.u[2] = tA; bu.u[3] = tB;
                #pragma unroll
                for (int f = 0; f < 4; ++f)
                    oacc[hh][f] = MFMA16(av[f][kc], bu.h, oacc[hh][f]);
            }
        }
        __builtin_amdgcn_s_setprio(0);
    }

    // epilogue: out^T layout -> float4 stores (4 consecutive dims per store)
    #pragma unroll
    for (int hh = 0; hh < 4; ++hh) {
        int hcol = (g * 4 + hh) * HDIM;
        #pragma unroll
        for (int f = 0; f < 4; ++f) {
            size_t row = (size_t)(b * SS + qt * 64 + w * 16 + ml);
            *reinterpret_cast<floatx4*>(&out[row * HIDDEN + hcol + f * 16 + lg * 4]) = oacc[hh][f];
        }
    }
}

extern "C" void kernel_launch(void* const* d_in, const int* in_sizes, int n_in,
                              void* d_out, int out_size, void* d_ws, size_t ws_size,
                              hipStream_t stream) {
    (void)in_sizes; (void)n_in; (void)out_size; (void)ws_size;
    const float* x    = (const float*)d_in[0];
    const int*   mask = (const int*)d_in[1];
    const float* Wq   = (const float*)d_in[2];
    const float* bq   = (const float*)d_in[3];
    const float* Wk   = (const float*)d_in[4];
    const float* bk   = (const float*)d_in[5];
    const float* Wv   = (const float*)d_in[6];
    const float* bv   = (const float*)d_in[7];

    _Float16* ws16 = (_Float16*)d_ws;
    size_t o = 0;
    auto alloc16 = [&](size_t n) { _Float16* p = ws16 + o; o += n; return p; };
    _Float16* xh  = alloc16((size_t)MROWS * HIDDEN);
    _Float16* xl  = alloc16((size_t)MROWS * HIDDEN);
    _Float16* Wth = alloc16((size_t)NQKV * HIDDEN);
    _Float16* Wtl = alloc16((size_t)NQKV * HIDDEN);
    _Float16* qh  = alloc16((size_t)MROWS * HIDDEN);
    _Float16* ql  = alloc16((size_t)MROWS * HIDDEN);
    _Float16* khs = alloc16((size_t)MROWS * KVDIM);
    _Float16* kls = alloc16((size_t)MROWS * KVDIM);
    _Float16* vh  = alloc16((size_t)MROWS * KVDIM);
    float* biascat = (float*)(ws16 + o);

    split_x<<<2048, 256, 0, stream>>>(x, xh, xl, MROWS * HIDDEN / 4);
    split_wt<<<dim3(32, 32), 256, 0, stream>>>(Wq, HIDDEN, 0,    Wth, Wtl);
    split_wt<<<dim3(32, 8),  256, 0, stream>>>(Wk, KVDIM, 2048, Wth, Wtl);
    split_wt<<<dim3(32, 8),  256, 0, stream>>>(Wv, KVDIM, 2560, Wth, Wtl);
    biascat_k<<<12, 256, 0, stream>>>(bq, bk, bv, biascat);
    gemm_qkv<<<dim3(MROWS / 128, NQKV / 128), 256, 0, stream>>>(
        xh, xl, Wth, Wtl, biascat, qh, ql, khs, kls, vh);
    attn5<<<dim3(32, 16), 256, 0, stream>>>(qh, ql, khs, kls, vh, mask, (float*)d_out);
}